// Round 4
// baseline (541.232 us; speedup 1.0000x reference)
//
#include <hip/hip_runtime.h>

// SSIM map — LDS-free rolling-register kernel.
// B=16, C=3, H=W=512, 11-tap separable gaussian (sigma=1.5).
//
// One wave produces a 64-col x 32-row output band. Per input row each lane
// loads its own 11-col window (x and y) directly from global — 22 coalesced
// dword loads sharing one address VGPR + immediate offsets; the overlapping
// taps are served by L1. Horizontal 11-tap conv of 5 fields (x,y,xx,yy,xy)
// in registers; vertical 11-tap conv via 11x5 rolling register accumulators
// (static mod-11 slot indexing from the unrolled 11-phase loop); SSIM
// epilogue with v_rcp_f32. Depth-1 row software pipeline: row rr+1's loads
// are issued before row rr's vertical/epilogue, consumed after.
//
// NO LDS anywhere (rounds 2/3 were latency-bound on a per-row LDS
// write->lgkmcnt(0)->read round-trip at ~3.5 resident waves/CU).
// Image-edge column handling is hoisted and templated: interior strips
// (1..6) pay zero predication; edge strips (0,7) use precomputed clamped
// offsets + loop-invariant masks. Two launches.

#define W    512
#define H    512
#define BC   48
#define RPB  32               // output rows per wave
#define NROWS (RPB + 10)      // 42 input rows per band
#define NBANDS (H / RPB)      // 16

template<bool EDGE>
__global__ __launch_bounds__(64, 4) void ssim_kernel(
    const float* __restrict__ x, const float* __restrict__ y,
    float* __restrict__ out, int strip0)
{
    // fp32-normalized gaussian, sigma=1.5, K=11 (matches np reference ~1e-7)
    const float g[11] = {
        0.00102838f, 0.00759875f, 0.03600077f, 0.10936069f, 0.21300553f,
        0.26601172f,
        0.21300553f, 0.10936069f, 0.03600077f, 0.00759875f, 0.00102838f};

    const int lane = threadIdx.x;                 // 0..63
    const int strip = EDGE ? (blockIdx.x == 0 ? 0 : 7) : (strip0 + blockIdx.x);
    const int band  = blockIdx.y;                 // 0..15
    const int bc    = blockIdx.z;                 // 0..47

    const int col0 = strip * 64;
    const int r0   = band * RPB;
    const int oc   = col0 + lane;                 // this lane's output col

    const float* __restrict__ xp = x + (size_t)bc * H * W;
    const float* __restrict__ yp = y + (size_t)bc * H * W;
    float* __restrict__ op = out + (size_t)bc * H * W + oc;

    // loop-invariant per-lane tap columns (+ clamp/mask for edge strips)
    int  cc[11];
    bool okc[11];
#pragma unroll
    for (int k = 0; k < 11; ++k) {
        const int c = oc - 5 + k;
        okc[k] = (c >= 0) && (c < W);
        cc[k]  = EDGE ? min(max(c, 0), W - 1) : c;
    }

    // rolling vertical accumulators: slot j holds the in-flight output row
    // with (o - r0 + 5) mod 11 == j; 5 fields each. Slot lifecycle is driven
    // by tap index m: m==0 assigns (fresh), m==10 completes (emit).
    float acc[11][5];
#pragma unroll
    for (int j = 0; j < 11; ++j)
#pragma unroll
        for (int f = 0; f < 5; ++f) acc[j][f] = 0.f;

    float vx[11], vy[11];            // raw taps of the row in flight
    float hx, hy, hxx, hyy, hxy;     // h-conv of the current row

    auto loadrow = [&](int rr) {
        const int r = r0 - 5 + rr;               // wave-uniform
        if (r >= 0 && r < H) {
            const float* __restrict__ xr = xp + (size_t)r * W;
            const float* __restrict__ yr = yp + (size_t)r * W;
#pragma unroll
            for (int k = 0; k < 11; ++k) {
                float a = xr[cc[k]];
                float b = yr[cc[k]];
                if (EDGE) { a = okc[k] ? a : 0.f; b = okc[k] ? b : 0.f; }
                vx[k] = a; vy[k] = b;
            }
        } else {
#pragma unroll
            for (int k = 0; k < 11; ++k) { vx[k] = 0.f; vy[k] = 0.f; }
        }
    };

    auto hconv = [&]() {
        float a0 = 0.f, a1 = 0.f, a2 = 0.f, a3 = 0.f, a4 = 0.f;
#pragma unroll
        for (int k = 0; k < 11; ++k) {
            const float w = g[k], a = vx[k], b = vy[k];
            a0 += w * a;
            a1 += w * b;
            a2 += w * (a * a);
            a3 += w * (b * b);
            a4 += w * (a * b);
        }
        hx = a0; hy = a1; hxx = a2; hyy = a3; hxy = a4;
    };

    loadrow(0);
    hconv();                                     // h of row rr=0

    // input rows rr = 0..41  ->  r = r0-5 .. r0+36
#pragma unroll 1
    for (int outer = 0; outer < 4; ++outer) {
#pragma unroll
        for (int ph = 0; ph < 11; ++ph) {
            const int rr = outer * 11 + ph;
            if (rr < NROWS) {                    // wave-uniform guard
                // issue next row's 22 loads (consumed by hconv at the end)
                if (rr + 1 < NROWS) loadrow(rr + 1);

                // vertical accumulate current row's h into the 11 slots;
                // m = tap index of slot j at this phase; m==0 starts a slot
#pragma unroll
                for (int j = 0; j < 11; ++j) {
                    const int   m = (ph - j + 16) % 11;
                    const float w = g[m];
                    if (m == 0) {
                        acc[j][0] = w * hx;  acc[j][1] = w * hy;
                        acc[j][2] = w * hxx; acc[j][3] = w * hyy;
                        acc[j][4] = w * hxy;
                    } else {
                        acc[j][0] += w * hx;  acc[j][1] += w * hy;
                        acc[j][2] += w * hxx; acc[j][3] += w * hyy;
                        acc[j][4] += w * hxy;
                    }
                }

                // slot (ph+6)%11 just took its m==10 tap: output row rr-10
                const int jc = (ph + 6) % 11;
                if (rr >= 10) {
                    const float mu1   = acc[jc][0];
                    const float mu2   = acc[jc][1];
                    const float mu1sq = mu1 * mu1;
                    const float mu2sq = mu2 * mu2;
                    const float mu12  = mu1 * mu2;
                    const float s1    = acc[jc][2] - mu1sq;
                    const float s2    = acc[jc][3] - mu2sq;
                    const float s12   = acc[jc][4] - mu12;
                    const float num = (2.f * mu12 + 1e-4f) * (2.f * s12 + 9e-4f);
                    const float den = (mu1sq + mu2sq + 1e-4f) * (s1 + s2 + 9e-4f);
                    op[(size_t)(r0 + rr - 10) * W] =
                        num * __builtin_amdgcn_rcpf(den);
                }

                // h-conv of the prefetched row (vmcnt wait lands here)
                if (rr + 1 < NROWS) hconv();
            }
        }
    }
}

extern "C" void kernel_launch(void* const* d_in, const int* in_sizes, int n_in,
                              void* d_out, int out_size, void* d_ws, size_t ws_size,
                              hipStream_t stream) {
    const float* img_out    = (const float*)d_in[0];
    const float* img_target = (const float*)d_in[1];
    // d_in[2] is window_size==11; fixed by the problem, baked into the kernel.
    float* out = (float*)d_out;

    // interior strips 1..6: no column predication
    dim3 gin(6, NBANDS, BC);    // 4608 one-wave blocks
    ssim_kernel<false><<<gin, 64, 0, stream>>>(img_out, img_target, out, 1);
    // edge strips 0 and 7: clamped offsets + masks
    dim3 ged(2, NBANDS, BC);    // 1536 one-wave blocks
    ssim_kernel<true><<<ged, 64, 0, stream>>>(img_out, img_target, out, 0);
}

// Round 5
// 218.048 us; speedup vs baseline: 2.4822x; 2.4822x over previous
//
#include <hip/hip_runtime.h>

// SSIM map — fused 3-stage tile kernel (round-1 structure, issue-optimized).
// B=16, C=3, H=W=512, 11-tap separable gaussian (sigma=1.5).
//
// Per 256-thread block: 32x32 output tile.
//   Stage 1: global -> LDS float2(x,y), 42x42 halo tile, zero-padded.
//   Stage 2: horizontal 11-tap conv; each thread computes 4 CONSECUTIVE cols
//            from 14 register-cached taps (products computed once per tap,
//            not once per tap*output). Writes float4(x,y,xx,yy)+float(xy).
//   Stage 3: vertical 11-tap conv; each thread computes 4 CONSECUTIVE rows,
//            each hf row read once (b128+b32) and reused by all 4 outputs.
//            SSIM epilogue with v_rcp_f32, coalesced store.
// Exactly 2 __syncthreads per block lifetime. LDS pitches chosen for
// bank-uniform access (sbuf pitch 43 odd; hf pitch 33). 41.2 KB LDS ->
// 3 blocks/CU = 12 waves/CU. No launch_bounds reg cap (round 4's spill trap).

#define W    512
#define H    512
#define BC   48
#define TX   32
#define TY   32
#define IX   42          // TX + 10
#define IY   42          // TY + 10
#define SP   43          // sbuf float2 pitch
#define HP   33          // hf pitch

__global__ __launch_bounds__(256) void ssim_kernel(
    const float* __restrict__ x, const float* __restrict__ y,
    float* __restrict__ out)
{
    __shared__ float2 sbuf[IY][SP];   // 14448 B: raw (x,y), halo tile
    __shared__ float4 hf4[IY][HP];    // 22176 B: h-conv (x,y,xx,yy)
    __shared__ float  hfx[IY][HP];    //  5544 B: h-conv (xy)

    // fp32-normalized gaussian, sigma=1.5, K=11 (matches np reference ~1e-7)
    const float g[11] = {
        0.00102838f, 0.00759875f, 0.03600077f, 0.10936069f, 0.21300553f,
        0.26601172f,
        0.21300553f, 0.10936069f, 0.03600077f, 0.00759875f, 0.00102838f};

    const int tid = threadIdx.x;
    const int bc  = blockIdx.z;
    const int c0  = blockIdx.x * TX;
    const int r0  = blockIdx.y * TY;

    const float* __restrict__ xp = x + (size_t)bc * H * W;
    const float* __restrict__ yp = y + (size_t)bc * H * W;

    // ---- Stage 1: global -> LDS, zero-padded halo tile ----
#pragma unroll
    for (int it = 0; it < 7; ++it) {
        const int idx = tid + it * 256;
        if (idx < IY * IX) {
            const int r  = idx / IX;
            const int c  = idx - r * IX;
            const int gr = r0 - 5 + r;
            const int gc = c0 - 5 + c;
            float vx = 0.f, vy = 0.f;
            if ((unsigned)gr < (unsigned)H && (unsigned)gc < (unsigned)W) {
                const size_t gi = (size_t)gr * W + gc;
                vx = xp[gi];
                vy = yp[gi];
            }
            sbuf[r][c] = make_float2(vx, vy);
        }
    }
    __syncthreads();

    // ---- Stage 2: horizontal conv, 4 consecutive cols per thread ----
    // item = row * 8 + colgroup; 42 rows x 8 groups = 336 items
#pragma unroll
    for (int it = 0; it < 2; ++it) {
        const int item = tid + it * 256;
        if (item < IY * 8) {
            const int row = item >> 3;
            const int cb  = (item & 7) << 2;     // base output col 0..28

            float2 v[14];
#pragma unroll
            for (int kk = 0; kk < 14; ++kk) v[kk] = sbuf[row][cb + kk];

            float a[4][5];
#pragma unroll
            for (int kk = 0; kk < 14; ++kk) {
                const float px  = v[kk].x, py = v[kk].y;
                const float pxx = px * px;
                const float pyy = py * py;
                const float pxy = px * py;
#pragma unroll
                for (int j = 0; j < 4; ++j) {
                    const int m = kk - j;        // tap index for output j
                    if (m >= 0 && m <= 10) {
                        const float w = g[m];
                        if (kk == j) {           // first tap: assign
                            a[j][0] = w * px;  a[j][1] = w * py;
                            a[j][2] = w * pxx; a[j][3] = w * pyy;
                            a[j][4] = w * pxy;
                        } else {
                            a[j][0] += w * px;  a[j][1] += w * py;
                            a[j][2] += w * pxx; a[j][3] += w * pyy;
                            a[j][4] += w * pxy;
                        }
                    }
                }
            }
#pragma unroll
            for (int j = 0; j < 4; ++j) {
                hf4[row][cb + j] = make_float4(a[j][0], a[j][1], a[j][2], a[j][3]);
                hfx[row][cb + j] = a[j][4];
            }
        }
    }
    __syncthreads();

    // ---- Stage 3: vertical conv + SSIM, 4 consecutive rows per thread ----
    {
        const int tx    = tid & 31;
        const int obase = (tid >> 5) << 2;       // first output row 0,4,..,28

        float acc[4][5];
#pragma unroll
        for (int rr = 0; rr < 14; ++rr) {
            const float4 h4 = hf4[obase + rr][tx];
            const float  h5 = hfx[obase + rr][tx];
#pragma unroll
            for (int j = 0; j < 4; ++j) {
                const int m = rr - j;            // tap index for output j
                if (m >= 0 && m <= 10) {
                    const float w = g[m];
                    if (rr == j) {
                        acc[j][0] = w * h4.x; acc[j][1] = w * h4.y;
                        acc[j][2] = w * h4.z; acc[j][3] = w * h4.w;
                        acc[j][4] = w * h5;
                    } else {
                        acc[j][0] += w * h4.x; acc[j][1] += w * h4.y;
                        acc[j][2] += w * h4.z; acc[j][3] += w * h4.w;
                        acc[j][4] += w * h5;
                    }
                }
            }
        }

        float* __restrict__ op = out + (size_t)bc * H * W;
#pragma unroll
        for (int j = 0; j < 4; ++j) {
            const float mu1   = acc[j][0];
            const float mu2   = acc[j][1];
            const float mu1sq = mu1 * mu1;
            const float mu2sq = mu2 * mu2;
            const float mu12  = mu1 * mu2;
            const float s1    = acc[j][2] - mu1sq;
            const float s2    = acc[j][3] - mu2sq;
            const float s12   = acc[j][4] - mu12;
            const float num = (2.f * mu12 + 1e-4f) * (2.f * s12 + 9e-4f);
            const float den = (mu1sq + mu2sq + 1e-4f) * (s1 + s2 + 9e-4f);
            op[(size_t)(r0 + obase + j) * W + c0 + tx] =
                num * __builtin_amdgcn_rcpf(den);
        }
    }
}

extern "C" void kernel_launch(void* const* d_in, const int* in_sizes, int n_in,
                              void* d_out, int out_size, void* d_ws, size_t ws_size,
                              hipStream_t stream) {
    const float* img_out    = (const float*)d_in[0];
    const float* img_target = (const float*)d_in[1];
    // d_in[2] is window_size==11; fixed by the problem, baked into the kernel.
    float* out = (float*)d_out;

    dim3 grid(W / TX, H / TY, BC);   // 16 x 16 x 48 = 12288 blocks
    ssim_kernel<<<grid, 256, 0, stream>>>(img_out, img_target, out);
}